// Round 11
// baseline (801.888 us; speedup 1.0000x reference)
//
#include <hip/hip_runtime.h>
#include <hip/hip_fp16.h>
#include <stdint.h>

#define T_STEPS 8
#define FIN 3
#define HID 32
#define NEG_SLOPE 0.2f
#define LOG2E 1.4426950408889634f

__device__ __forceinline__ float lrelu(float x) { return x > 0.f ? x : NEG_SLOPE * x; }
__device__ __forceinline__ float sigmoidf(float x) { return 1.f / (1.f + __expf(-x)); }

// ---------------- edge dtype detection (int64 vs int32) ----------------
__global__ void detect_kernel(const int* ei32, int nElems, int* flag) {
    __shared__ int any_nonzero;
    if (threadIdx.x == 0) any_nonzero = 0;
    __syncthreads();
    int idx = 1 + 2 * (int)threadIdx.x;  // odd int32 slots
    if (idx < nElems && ei32[idx] != 0) any_nonzero = 1;  // benign race
    __syncthreads();
    if (threadIdx.x == 0) *flag = (any_nonzero ? 0 : 1);  // 1 => int64
}

__device__ __forceinline__ int get_edge(const void* ei, int is64, long long idx) {
    if (is64) return (int)((const long long*)ei)[idx];
    return ((const int*)ei)[idx];
}

__global__ void init_kernel(int* cnt, int N) {
    int i = blockIdx.x * 256 + threadIdx.x;
    if (i < N) cnt[i] = 1;  // self-loop pre-counted
}

// fused: int32 conversion + validity clamp + per-dst count
__global__ void conv_count_kernel(const void* ei, const int* flag, int E, int N,
                                  int* src32, int* dst32, int* cnt) {
    int e = blockIdx.x * 256 + threadIdx.x;
    if (e >= E) return;
    int is64 = *flag;
    int s = get_edge(ei, is64, e);
    int d = get_edge(ei, is64, (long long)E + e);
    if ((unsigned)s >= (unsigned)N) s = 0;  // safety clamp
    src32[e] = s;
    int dd = ((unsigned)d < (unsigned)N) ? d : 0x7fffffff;  // sentinel: excluded everywhere
    dst32[e] = dd;
    if (dd < N) atomicAdd(&cnt[dd], 1);
}

// hierarchical scan
__global__ __launch_bounds__(256) void scan1_kernel(const int* cnt, int* rowptr, int* bsum, int n) {
    __shared__ int sm[256];
    int i = blockIdx.x * 256 + threadIdx.x;
    int v = (i < n) ? cnt[i] : 0;
    sm[threadIdx.x] = v;
    __syncthreads();
    for (int off = 1; off < 256; off <<= 1) {
        int t = (threadIdx.x >= off) ? sm[threadIdx.x - off] : 0;
        __syncthreads();
        sm[threadIdx.x] += t;
        __syncthreads();
    }
    if (i < n) rowptr[i + 1] = sm[threadIdx.x];
    if (threadIdx.x == 255) bsum[blockIdx.x] = sm[255];
}

__global__ __launch_bounds__(256) void scan2_kernel(int* bsum, int nb) {
    __shared__ int sm[256];
    int v = (threadIdx.x < nb) ? bsum[threadIdx.x] : 0;
    sm[threadIdx.x] = v;
    __syncthreads();
    for (int off = 1; off < 256; off <<= 1) {
        int t = (threadIdx.x >= off) ? sm[threadIdx.x - off] : 0;
        __syncthreads();
        sm[threadIdx.x] += t;
        __syncthreads();
    }
    if (threadIdx.x < nb) bsum[threadIdx.x] = sm[threadIdx.x];
}

__global__ __launch_bounds__(256) void scan3_kernel(int* rowptr, const int* bsum, int n) {
    int i = blockIdx.x * 256 + threadIdx.x;
    if (i < n && blockIdx.x > 0) rowptr[i + 1] += bsum[blockIdx.x - 1];
    if (i == 0) rowptr[0] = 0;
}

__global__ void selffill_kernel(const int* rowptr, int* csr, int* fill, int N) {
    int n = blockIdx.x * 256 + threadIdx.x;
    if (n >= N) return;
    int rp = rowptr[n];
    csr[rp] = n;        // self-loop occupies slot 0 of each row
    fill[n] = rp + 1;
}

// dst-sliced scatter: csr writes confined to an L2-resident window per pass
__global__ void scatter_kernel(const int* __restrict__ src32, const int* __restrict__ dst32,
                               int E, int lo, int hi, int* fill, int* csr) {
    int e = blockIdx.x * 256 + threadIdx.x;
    if (e >= E) return;
    int d = dst32[e];
    if (d < lo || d >= hi) return;
    int p = atomicAdd(&fill[d], 1);
    csr[p] = src32[e];
}

// ---------------- precompute u = (W2^T a2) * log2(e) per head ----------------
__global__ __launch_bounds__(64) void prep_u_kernel(
        const float* __restrict__ W2, const float* __restrict__ a2s,
        const float* __restrict__ a2d, float* __restrict__ u_s, float* __restrict__ u_d) {
    int l = threadIdx.x;  // 0..63
    int h = l >> 5, k = l & 31;
    float us = 0.f, ud = 0.f;
    for (int c = 0; c < 32; c++) {
        float w = W2[(h * 32 + c) * 32 + k];
        us += a2s[h * 32 + c] * w;
        ud += a2d[h * 32 + c] * w;
    }
    u_s[l] = us * LOG2E;   // exp2 trick: lrelu is positively homogeneous
    u_d[l] = ud * LOG2E;
}

// ---------------- pack weights k-major for the dense phase ----------------
__global__ __launch_bounds__(256) void pack_kernel(
        const float* __restrict__ W2, const float* __restrict__ w_ih,
        const float* __restrict__ w_hh, float* __restrict__ w2pk, float* __restrict__ wgru) {
    int idx = blockIdx.x * 256 + threadIdx.x;
    if (idx < 2048) {
        int k = idx >> 6, c = idx & 63;
        w2pk[idx] = W2[c * 32 + k];
    }
    if (idx < 6144) {
        int k = idx / 192, r = idx % 192;
        wgru[idx] = (r < 96) ? w_ih[r * 32 + k] : w_hh[(r - 96) * 32 + k];
    }
}

// ---------------- layer-1 scores: THREAD-per-node; scores pre-scaled by log2(e) ----------------
__global__ __launch_bounds__(256) void score1_kernel(
        const float* __restrict__ x, const float* __restrict__ W1,
        const float* __restrict__ a1s, const float* __restrict__ a1d,
        float4* __restrict__ nrec4, float2* __restrict__ sd1, int N) {
    int node = blockIdx.x * 256 + threadIdx.x;
    if (node >= N) return;
    const float* xp = x + (size_t)node * FIN;
    float x0 = xp[0], x1 = xp[1], x2 = xp[2];
    float ps0 = 0.f, ps1 = 0.f, pd0 = 0.f, pd1 = 0.f;
    for (int c = 0; c < 32; c++) {
        float h0 = W1[c * 3] * x0 + W1[c * 3 + 1] * x1 + W1[c * 3 + 2] * x2;
        float h1 = W1[96 + c * 3] * x0 + W1[97 + c * 3] * x1 + W1[98 + c * 3] * x2;
        ps0 += h0 * a1s[c]; pd0 += h0 * a1d[c];
        ps1 += h1 * a1s[32 + c]; pd1 += h1 * a1d[32 + c];
    }
    ps0 *= LOG2E; ps1 *= LOG2E; pd0 *= LOG2E; pd1 *= LOG2E;
    unsigned u = (unsigned)__half_as_ushort(__float2half_rn(ps0)) |
                 ((unsigned)__half_as_ushort(__float2half_rn(ps1)) << 16);
    float4 r;
    r.x = x0; r.y = x1; r.z = x2; r.w = __uint_as_float(u);
    nrec4[node] = r;
    sd1[node] = make_float2(pd0, pd1);
}

__device__ __forceinline__ void unpack_scores(float wslot, float& s0, float& s1) {
    unsigned u = __float_as_uint(wslot);
    s0 = __half2float(__ushort_as_half((unsigned short)(u & 0xffffu)));
    s1 = __half2float(__ushort_as_half((unsigned short)(u >> 16)));
}

// ---------------- GAT1 aggregate: PAIR-per-dst (2 threads split edges) ----------------
// 2N threads -> 1563 waves (~6/CU). Pair merges via shfl_xor(1); epilogue splits 16+16 ch.
__global__ __launch_bounds__(256) void aggA_kernel(
        const int* __restrict__ rowptr, const int* __restrict__ csr,
        const float4* __restrict__ nrec4, const float2* __restrict__ sd1,
        const float* __restrict__ W1, const float* __restrict__ b1,
        const float* __restrict__ u_s, const float* __restrict__ u_d,
        __half2* __restrict__ g1h, float2* __restrict__ ssd2, float2* __restrict__ sd2, int N) {
    int t2 = blockIdx.x * 256 + threadIdx.x;
    int dst = t2 >> 1;
    if (dst >= N) return;
    int half = t2 & 1;
    int rs = rowptr[dst], re = rowptr[dst + 1];
    float2 sdv = sd1[dst];
    float q0 = 0, qx0 = 0, qx1 = 0, qx2 = 0;
    float q1 = 0, qy0 = 0, qy1 = 0, qy2 = 0;
#define AGGA_EDGE(rr) { \
        float s0h, s1h; unpack_scores(rr.w, s0h, s1h); \
        float w0 = exp2f(lrelu(s0h + sdv.x)); \
        float w1 = exp2f(lrelu(s1h + sdv.y)); \
        q0 += w0; qx0 += w0 * rr.x; qx1 += w0 * rr.y; qx2 += w0 * rr.z; \
        q1 += w1; qy0 += w1 * rr.x; qy1 += w1 * rr.y; qy2 += w1 * rr.z; }
    int e = rs + half;
    for (; e + 2 < re; e += 4) {  // two edges in flight per thread (pair covers 4)
        int s0 = csr[e], s1 = csr[e + 2];
        float4 r0 = nrec4[s0], r1 = nrec4[s1];
        AGGA_EDGE(r0); AGGA_EDGE(r1);
    }
    for (; e < re; e += 2) {
        int s = csr[e];
        float4 r = nrec4[s];
        AGGA_EDGE(r);
    }
#undef AGGA_EDGE
    // merge pair
    q0 += __shfl_xor(q0, 1, 64);   qx0 += __shfl_xor(qx0, 1, 64);
    qx1 += __shfl_xor(qx1, 1, 64); qx2 += __shfl_xor(qx2, 1, 64);
    q1 += __shfl_xor(q1, 1, 64);   qy0 += __shfl_xor(qy0, 1, 64);
    qy1 += __shfl_xor(qy1, 1, 64); qy2 += __shfl_xor(qy2, 1, 64);
    float inv0 = 1.f / (q0 + 1e-16f), inv1 = 1.f / (q1 + 1e-16f);
    float ax0 = qx0 * inv0, ax1 = qx1 * inv0, ax2 = qx2 * inv0;
    float ay0 = qy0 * inv1, ay1 = qy1 * inv1, ay2 = qy2 * inv1;
    float ps0 = 0, ps1 = 0, pd0 = 0, pd1 = 0;
    float4 out[2];
    __half2* ghp = (__half2*)out;
    float gprev = 0.f;
#pragma unroll
    for (int cc = 0; cc < 16; cc++) {
        int c = half * 16 + cc;
        float v0 = W1[c * 3] * ax0 + W1[c * 3 + 1] * ax1 + W1[c * 3 + 2] * ax2;
        float v1 = W1[96 + c * 3] * ay0 + W1[97 + c * 3] * ay1 + W1[98 + c * 3] * ay2;
        float g = fmaxf(0.5f * (v0 + v1) + b1[c], 0.f);  // mean heads + bias + relu
        ps0 += g * u_s[c];      ps1 += g * u_s[32 + c];   // u_* already log2e-scaled
        pd0 += g * u_d[c];      pd1 += g * u_d[32 + c];
        if (cc & 1) ghp[cc >> 1] = __floats2half2_rn(gprev, g);
        else gprev = g;
    }
    float4* gdst = (float4*)(g1h + (size_t)dst * 16);
    gdst[half * 2] = out[0];
    gdst[half * 2 + 1] = out[1];
    ps0 += __shfl_xor(ps0, 1, 64); ps1 += __shfl_xor(ps1, 1, 64);
    pd0 += __shfl_xor(pd0, 1, 64); pd1 += __shfl_xor(pd1, 1, 64);
    if (half == 0) {
        ssd2[dst] = make_float2(ps0, ps1);
        sd2[dst]  = make_float2(pd0, pd1);
    }
}

// ---------------- FUSED: GAT2 aggregate (octet-per-dst, 32 dsts/block) + W2 + GRU (+fc) ----------------
// 1563 blocks (~6/CU), LDS 12.7KB -> up to 24 waves/CU. Octet thread o owns channels 4o..4o+3.
__global__ __launch_bounds__(256, 6) void aggBdense_kernel(
        const int* __restrict__ rowptr, const int* __restrict__ csr,
        const __half2* __restrict__ g1h,
        const float2* __restrict__ ssd2, const float2* __restrict__ sd2,
        const float* __restrict__ w2pk, const float* __restrict__ b2,
        const float* __restrict__ wgru,
        const float* __restrict__ b_ih, const float* __restrict__ b_hh,
        float* __restrict__ hstT, const float* __restrict__ fc_w,
        const float* __restrict__ fc_b, float* __restrict__ out,
        int N, int first, int last) {
    __shared__ __half2 a_lds[32 * 33];   // [dst][pair]: 0-15 head0 agg, 16-31 head1 agg
    __shared__ float g_lds[32 * 33];     // [nl][c] (reused for fc partials on last)
    __shared__ float h_lds[32 * 33];     // [nl][k]
    int tid = threadIdx.x;
    int node0 = blockIdx.x * 32;
    // stage previous h state (coalesced: node fastest, 32 lanes = 128B)
    for (int idx = tid; idx < 32 * 32; idx += 256) {
        int k = idx >> 5, nl = idx & 31;
        float hv = 0.f;
        if (!first && node0 + nl < N) hv = hstT[(size_t)k * N + node0 + nl];
        h_lds[nl * 33 + k] = hv;
    }
    // ---- phase 1: octet-per-dst GAT2 aggregation ----
    int dl = tid >> 3;           // local dst 0..31
    int o = tid & 7;             // octet lane: channels 4o..4o+3 (half2 pairs 2o, 2o+1)
    int dst = node0 + dl;
    if (dst < N) {
        int rs = rowptr[dst], re = rowptr[dst + 1];
        float2 sdv = sd2[dst];
        float a0[4] = {0, 0, 0, 0};
        float a1[4] = {0, 0, 0, 0};
        float den0 = 0.f, den1 = 0.f;
        const __half2* gbase = g1h + o * 2;  // this thread's 2 half2 slots of each row
#define AGGB_EDGE(sc, gv) { \
        float w0 = exp2f(lrelu(sc.x + sdv.x)); \
        float w1 = exp2f(lrelu(sc.y + sdv.y)); \
        den0 += w0; den1 += w1; \
        float2 p0 = __half22float2(*(const __half2*)&gv.x); \
        float2 p1 = __half22float2(*(const __half2*)&gv.y); \
        a0[0] += w0 * p0.x; a0[1] += w0 * p0.y; a0[2] += w0 * p1.x; a0[3] += w0 * p1.y; \
        a1[0] += w1 * p0.x; a1[1] += w1 * p0.y; a1[2] += w1 * p1.x; a1[3] += w1 * p1.y; }
        int e = rs;
        for (; e + 4 <= re; e += 4) {
            int s0 = csr[e], s1 = csr[e + 1], s2 = csr[e + 2], s3 = csr[e + 3];
            float2 c0 = ssd2[s0], c1 = ssd2[s1], c2 = ssd2[s2], c3 = ssd2[s3];
            uint2 g0 = *(const uint2*)(gbase + (size_t)s0 * 16);
            uint2 g1 = *(const uint2*)(gbase + (size_t)s1 * 16);
            uint2 g2 = *(const uint2*)(gbase + (size_t)s2 * 16);
            uint2 g3 = *(const uint2*)(gbase + (size_t)s3 * 16);
            AGGB_EDGE(c0, g0); AGGB_EDGE(c1, g1); AGGB_EDGE(c2, g2); AGGB_EDGE(c3, g3);
        }
        for (; e < re; e++) {
            int s = csr[e];
            float2 c = ssd2[s];
            uint2 g = *(const uint2*)(gbase + (size_t)s * 16);
            AGGB_EDGE(c, g);
        }
#undef AGGB_EDGE
        float i0 = 1.f / (den0 + 1e-16f), i1 = 1.f / (den1 + 1e-16f);
        a_lds[dl * 33 + 2 * o]          = __floats2half2_rn(a0[0] * i0, a0[1] * i0);
        a_lds[dl * 33 + 2 * o + 1]      = __floats2half2_rn(a0[2] * i0, a0[3] * i0);
        a_lds[dl * 33 + 16 + 2 * o]     = __floats2half2_rn(a1[0] * i1, a1[1] * i1);
        a_lds[dl * 33 + 16 + 2 * o + 1] = __floats2half2_rn(a1[2] * i1, a1[3] * i1);
    }
    __syncthreads();
    // ---- phase 2: W2 + mean-heads + relu (8 threads/node, 4 channels each) ----
    int nl = tid & 31;
    int cg4 = (tid >> 5) * 4;   // channel base 0,4,...,28 (half-wave uniform -> L1 broadcast)
    int node = node0 + nl;
    bool active = node < N;
    float acc[4] = {0, 0, 0, 0};
    for (int kp = 0; kp < 16; kp++) {
        float2 A0 = __half22float2(a_lds[nl * 33 + kp]);        // head0 agg ch 2kp, 2kp+1
        float2 A1 = __half22float2(a_lds[nl * 33 + 16 + kp]);   // head1 agg ch 2kp, 2kp+1
        const float* wpA = w2pk + (2 * kp) * 64 + cg4;
        const float* wpB = w2pk + (2 * kp + 1) * 64 + cg4;
#pragma unroll
        for (int j = 0; j < 4; j++)
            acc[j] += wpA[j] * A0.x + wpA[32 + j] * A1.x + wpB[j] * A0.y + wpB[32 + j] * A1.y;
    }
#pragma unroll
    for (int j = 0; j < 4; j++) {
        float g = fmaxf(0.5f * acc[j] + b2[cg4 + j], 0.f);
        g_lds[nl * 33 + cg4 + j] = g;
    }
    __syncthreads();
    // ---- GRU for channels cg4..cg4+3 ----
    float ir[4], iz[4], in_[4], hr[4], hz[4], hn[4];
#pragma unroll
    for (int j = 0; j < 4; j++) {
        ir[j] = b_ih[cg4 + j]; iz[j] = b_ih[32 + cg4 + j]; in_[j] = b_ih[64 + cg4 + j];
        hr[j] = b_hh[cg4 + j]; hz[j] = b_hh[32 + cg4 + j]; hn[j] = b_hh[64 + cg4 + j];
    }
    for (int k = 0; k < 32; k++) {
        float gk = g_lds[nl * 33 + k];
        float hk = h_lds[nl * 33 + k];
        const float* wp = wgru + k * 192 + cg4;
#pragma unroll
        for (int j = 0; j < 4; j++) {
            ir[j]  += wp[j]       * gk;
            iz[j]  += wp[32 + j]  * gk;
            in_[j] += wp[64 + j]  * gk;
            hr[j]  += wp[96 + j]  * hk;
            hz[j]  += wp[128 + j] * hk;
            hn[j]  += wp[160 + j] * hk;
        }
    }
    float part = 0.f;
    if (active) {
#pragma unroll
        for (int j = 0; j < 4; j++) {
            int c = cg4 + j;
            float rr = sigmoidf(ir[j] + hr[j]);
            float zz = sigmoidf(iz[j] + hz[j]);
            float cand = tanhf(in_[j] + rr * hn[j]);
            float hold = h_lds[nl * 33 + c];
            float hnew = (1.f - zz) * cand + zz * hold;
            if (!last) hstT[(size_t)c * N + node] = hnew;
            else part += fc_w[c] * hnew;
        }
    }
    if (last) {
        __syncthreads();  // g_lds no longer needed; reuse for fc partials
        g_lds[nl * 33 + (tid >> 5)] = part;
        __syncthreads();
        if (tid < 32 && node0 + tid < N) {
            const float* pr = g_lds + tid * 33;
            float v = pr[0] + pr[1] + pr[2] + pr[3] + pr[4] + pr[5] + pr[6] + pr[7] + fc_b[0];
            out[node0 + tid] = v;
        }
    }
}

extern "C" void kernel_launch(void* const* d_in, const int* in_sizes, int n_in,
                              void* d_out, int out_size, void* d_ws, size_t ws_size,
                              hipStream_t stream) {
    const float* x_seq = (const float*)d_in[0];
    const float* W1  = (const float*)d_in[1];
    const float* a1s = (const float*)d_in[2];
    const float* a1d = (const float*)d_in[3];
    const float* b1  = (const float*)d_in[4];
    const float* W2  = (const float*)d_in[5];
    const float* a2s = (const float*)d_in[6];
    const float* a2d = (const float*)d_in[7];
    const float* b2  = (const float*)d_in[8];
    const float* w_ih = (const float*)d_in[9];
    const float* w_hh = (const float*)d_in[10];
    const float* b_ih = (const float*)d_in[11];
    const float* b_hh = (const float*)d_in[12];
    const float* fc_w = (const float*)d_in[13];
    const float* fc_b = (const float*)d_in[14];
    const void*  ei   = d_in[15];

    const int N = in_sizes[0] / (T_STEPS * FIN);  // 50000
    const int E = in_sizes[15] / 2;               // 800000
    const int NE = E + N;
    const int NB = (N + 255) / 256;               // per-256 blocks (196)
    const int NB32 = (N + 31) / 32;               // 32-node blocks (1563)
    const int EB = (E + 255) / 256;

    char* ws = (char*)d_ws;
    size_t off = 0;
    auto alloc = [&](size_t bytes) -> void* {
        void* p = ws + off;
        off += (bytes + 255) & ~(size_t)255;
        return p;
    };
    int*     flag   = (int*)alloc(4);
    int*     rowptr = (int*)alloc((size_t)(N + 1) * 4);
    int*     cnt    = (int*)alloc((size_t)N * 4);        // reused as fill cursor
    int*     bsum   = (int*)alloc(256 * 4);
    int*     csr    = (int*)alloc((size_t)NE * 4);
    int*     src32  = (int*)alloc((size_t)E * 4);
    int*     dst32  = (int*)alloc((size_t)E * 4);
    float4*  nrec4  = (float4*)alloc((size_t)N * 16);    // {x0,x1,x2,half2(ss0,ss1)*log2e}
    float2*  sd1    = (float2*)alloc((size_t)N * 8);
    float2*  ssd2   = (float2*)alloc((size_t)N * 8);
    float2*  sd2    = (float2*)alloc((size_t)N * 8);
    __half2* g1h    = (__half2*)alloc((size_t)N * 16 * 4);  // fp16 g1: 64B/node
    float*   hstT   = (float*)alloc((size_t)N * 32 * 4);    // transposed hstate [c][node]
    float*   u_s    = (float*)alloc(64 * 4);
    float*   u_d    = (float*)alloc(64 * 4);
    float*   w2pk   = (float*)alloc(2048 * 4);              // k-major W2
    float*   wgru   = (float*)alloc(6144 * 4);              // k-major GRU weights
    if (off > ws_size) return;  // workspace too small — cannot proceed safely

    // ---- preprocessing: CSR by destination (reused for all 16 aggregations) ----
    detect_kernel<<<1, 128, 0, stream>>>((const int*)ei, in_sizes[15], flag);
    init_kernel<<<NB, 256, 0, stream>>>(cnt, N);
    conv_count_kernel<<<EB, 256, 0, stream>>>(ei, flag, E, N, src32, dst32, cnt);
    scan1_kernel<<<NB, 256, 0, stream>>>(cnt, rowptr, bsum, N);
    scan2_kernel<<<1, 256, 0, stream>>>(bsum, NB);
    scan3_kernel<<<NB, 256, 0, stream>>>(rowptr, bsum, N);
    selffill_kernel<<<NB, 256, 0, stream>>>(rowptr, csr, cnt, N);
    {
        const int NPASS = 4;
        int per = (N + NPASS - 1) / NPASS;
        for (int p = 0; p < NPASS; p++) {
            int lo = p * per;
            int hi = min(lo + per, N);
            scatter_kernel<<<EB, 256, 0, stream>>>(src32, dst32, E, lo, hi, cnt, csr);
        }
    }
    prep_u_kernel<<<1, 64, 0, stream>>>(W2, a2s, a2d, u_s, u_d);
    pack_kernel<<<24, 256, 0, stream>>>(W2, w_ih, w_hh, w2pk, wgru);

    // ---- T timesteps ----
    for (int t = 0; t < T_STEPS; t++) {
        const float* xt = x_seq + (size_t)t * N * FIN;
        score1_kernel<<<NB, 256, 0, stream>>>(xt, W1, a1s, a1d, nrec4, sd1, N);
        aggA_kernel<<<(2 * N + 255) / 256, 256, 0, stream>>>(rowptr, csr, nrec4, sd1, W1, b1,
                                                             u_s, u_d, g1h, ssd2, sd2, N);
        aggBdense_kernel<<<NB32, 256, 0, stream>>>(rowptr, csr, g1h, ssd2, sd2,
                                                   w2pk, b2, wgru, b_ih, b_hh,
                                                   hstT, fc_w, fc_b, (float*)d_out,
                                                   N, t == 0 ? 1 : 0, t == T_STEPS - 1 ? 1 : 0);
    }
}

// Round 12
// 566.404 us; speedup vs baseline: 1.4158x; 1.4158x over previous
//
#include <hip/hip_runtime.h>
#include <hip/hip_fp16.h>
#include <stdint.h>

#define T_STEPS 8
#define FIN 3
#define HID 32
#define NEG_SLOPE 0.2f
#define LOG2E 1.4426950408889634f

__device__ __forceinline__ float lrelu(float x) { return x > 0.f ? x : NEG_SLOPE * x; }
__device__ __forceinline__ float sigmoidf(float x) { return 1.f / (1.f + __expf(-x)); }

// ---------------- edge dtype detection (int64 vs int32) ----------------
__global__ void detect_kernel(const int* ei32, int nElems, int* flag) {
    __shared__ int any_nonzero;
    if (threadIdx.x == 0) any_nonzero = 0;
    __syncthreads();
    int idx = 1 + 2 * (int)threadIdx.x;  // odd int32 slots
    if (idx < nElems && ei32[idx] != 0) any_nonzero = 1;  // benign race
    __syncthreads();
    if (threadIdx.x == 0) *flag = (any_nonzero ? 0 : 1);  // 1 => int64
}

__device__ __forceinline__ int get_edge(const void* ei, int is64, long long idx) {
    if (is64) return (int)((const long long*)ei)[idx];
    return ((const int*)ei)[idx];
}

__global__ void init_kernel(int* cnt, int N) {
    int i = blockIdx.x * 256 + threadIdx.x;
    if (i < N) cnt[i] = 1;  // self-loop pre-counted
}

// fused: int32 conversion + validity clamp + per-dst count
__global__ void conv_count_kernel(const void* ei, const int* flag, int E, int N,
                                  int* src32, int* dst32, int* cnt) {
    int e = blockIdx.x * 256 + threadIdx.x;
    if (e >= E) return;
    int is64 = *flag;
    int s = get_edge(ei, is64, e);
    int d = get_edge(ei, is64, (long long)E + e);
    if ((unsigned)s >= (unsigned)N) s = 0;  // safety clamp
    src32[e] = s;
    int dd = ((unsigned)d < (unsigned)N) ? d : 0x7fffffff;  // sentinel: excluded everywhere
    dst32[e] = dd;
    if (dd < N) atomicAdd(&cnt[dd], 1);
}

// hierarchical scan
__global__ __launch_bounds__(256) void scan1_kernel(const int* cnt, int* rowptr, int* bsum, int n) {
    __shared__ int sm[256];
    int i = blockIdx.x * 256 + threadIdx.x;
    int v = (i < n) ? cnt[i] : 0;
    sm[threadIdx.x] = v;
    __syncthreads();
    for (int off = 1; off < 256; off <<= 1) {
        int t = (threadIdx.x >= off) ? sm[threadIdx.x - off] : 0;
        __syncthreads();
        sm[threadIdx.x] += t;
        __syncthreads();
    }
    if (i < n) rowptr[i + 1] = sm[threadIdx.x];
    if (threadIdx.x == 255) bsum[blockIdx.x] = sm[255];
}

__global__ __launch_bounds__(256) void scan2_kernel(int* bsum, int nb) {
    __shared__ int sm[256];
    int v = (threadIdx.x < nb) ? bsum[threadIdx.x] : 0;
    sm[threadIdx.x] = v;
    __syncthreads();
    for (int off = 1; off < 256; off <<= 1) {
        int t = (threadIdx.x >= off) ? sm[threadIdx.x - off] : 0;
        __syncthreads();
        sm[threadIdx.x] += t;
        __syncthreads();
    }
    if (threadIdx.x < nb) bsum[threadIdx.x] = sm[threadIdx.x];
}

__global__ __launch_bounds__(256) void scan3_kernel(int* rowptr, const int* bsum, int n) {
    int i = blockIdx.x * 256 + threadIdx.x;
    if (i < n && blockIdx.x > 0) rowptr[i + 1] += bsum[blockIdx.x - 1];
    if (i == 0) rowptr[0] = 0;
}

__global__ void selffill_kernel(const int* rowptr, int* csr, int* fill, int N) {
    int n = blockIdx.x * 256 + threadIdx.x;
    if (n >= N) return;
    int rp = rowptr[n];
    csr[rp] = n;        // self-loop occupies slot 0 of each row
    fill[n] = rp + 1;
}

// dst-sliced scatter: csr writes confined to an L2-resident window per pass
__global__ void scatter_kernel(const int* __restrict__ src32, const int* __restrict__ dst32,
                               int E, int lo, int hi, int* fill, int* csr) {
    int e = blockIdx.x * 256 + threadIdx.x;
    if (e >= E) return;
    int d = dst32[e];
    if (d < lo || d >= hi) return;
    int p = atomicAdd(&fill[d], 1);
    csr[p] = src32[e];
}

// ---------------- per-64-tile degree rank sort: waves process similar-degree dsts ----------------
// perm[node0 + rank] = local index (descending degree). Bijective within each tile.
__global__ __launch_bounds__(64) void sortperm_kernel(const int* __restrict__ rowptr,
                                                      unsigned char* __restrict__ perm, int N) {
    __shared__ int deg[64];
    int node0 = blockIdx.x * 64;
    int i = threadIdx.x;
    int n = min(64, N - node0);
    int d = 0;
    if (i < n) d = rowptr[node0 + i + 1] - rowptr[node0 + i];
    deg[i] = d;
    __syncthreads();
    if (i < n) {
        int r = 0;
        for (int j = 0; j < n; j++) {
            int dj = deg[j];
            if (dj > d || (dj == d && j < i)) r++;
        }
        perm[node0 + r] = (unsigned char)i;
    }
}

// ---------------- precompute u = (W2^T a2) * log2(e) per head ----------------
__global__ __launch_bounds__(64) void prep_u_kernel(
        const float* __restrict__ W2, const float* __restrict__ a2s,
        const float* __restrict__ a2d, float* __restrict__ u_s, float* __restrict__ u_d) {
    int l = threadIdx.x;  // 0..63
    int h = l >> 5, k = l & 31;
    float us = 0.f, ud = 0.f;
    for (int c = 0; c < 32; c++) {
        float w = W2[(h * 32 + c) * 32 + k];
        us += a2s[h * 32 + c] * w;
        ud += a2d[h * 32 + c] * w;
    }
    u_s[l] = us * LOG2E;   // exp2 trick: lrelu is positively homogeneous
    u_d[l] = ud * LOG2E;
}

// ---------------- pack weights k-major for the dense phase ----------------
__global__ __launch_bounds__(256) void pack_kernel(
        const float* __restrict__ W2, const float* __restrict__ w_ih,
        const float* __restrict__ w_hh, float* __restrict__ w2pk, float* __restrict__ wgru) {
    int idx = blockIdx.x * 256 + threadIdx.x;
    if (idx < 2048) {
        int k = idx >> 6, c = idx & 63;
        w2pk[idx] = W2[c * 32 + k];
    }
    if (idx < 6144) {
        int k = idx / 192, r = idx % 192;
        wgru[idx] = (r < 96) ? w_ih[r * 32 + k] : w_hh[(r - 96) * 32 + k];
    }
}

// ---------------- layer-1 scores: THREAD-per-node; scores pre-scaled by log2(e) ----------------
__global__ __launch_bounds__(256) void score1_kernel(
        const float* __restrict__ x, const float* __restrict__ W1,
        const float* __restrict__ a1s, const float* __restrict__ a1d,
        float4* __restrict__ nrec4, float2* __restrict__ sd1, int N) {
    int node = blockIdx.x * 256 + threadIdx.x;
    if (node >= N) return;
    const float* xp = x + (size_t)node * FIN;
    float x0 = xp[0], x1 = xp[1], x2 = xp[2];
    float ps0 = 0.f, ps1 = 0.f, pd0 = 0.f, pd1 = 0.f;
    for (int c = 0; c < 32; c++) {
        float h0 = W1[c * 3] * x0 + W1[c * 3 + 1] * x1 + W1[c * 3 + 2] * x2;
        float h1 = W1[96 + c * 3] * x0 + W1[97 + c * 3] * x1 + W1[98 + c * 3] * x2;
        ps0 += h0 * a1s[c]; pd0 += h0 * a1d[c];
        ps1 += h1 * a1s[32 + c]; pd1 += h1 * a1d[32 + c];
    }
    ps0 *= LOG2E; ps1 *= LOG2E; pd0 *= LOG2E; pd1 *= LOG2E;
    unsigned u = (unsigned)__half_as_ushort(__float2half_rn(ps0)) |
                 ((unsigned)__half_as_ushort(__float2half_rn(ps1)) << 16);
    float4 r;
    r.x = x0; r.y = x1; r.z = x2; r.w = __uint_as_float(u);
    nrec4[node] = r;
    sd1[node] = make_float2(pd0, pd1);
}

__device__ __forceinline__ void unpack_scores(float wslot, float& s0, float& s1) {
    unsigned u = __float_as_uint(wslot);
    s0 = __half2float(__ushort_as_half((unsigned short)(u & 0xffffu)));
    s1 = __half2float(__ushort_as_half((unsigned short)(u >> 16)));
}

// ---------------- GAT1 aggregate: THREAD-per-dst (degree-sorted within tile) ----------------
__global__ __launch_bounds__(64) void aggA_kernel(
        const int* __restrict__ rowptr, const int* __restrict__ csr,
        const unsigned char* __restrict__ perm,
        const float4* __restrict__ nrec4, const float2* __restrict__ sd1,
        const float* __restrict__ W1, const float* __restrict__ b1,
        const float* __restrict__ u_s, const float* __restrict__ u_d,
        __half2* __restrict__ g1h, float2* __restrict__ ssd2, float2* __restrict__ sd2, int N) {
    int node0 = blockIdx.x * 64;
    if (node0 + (int)threadIdx.x >= N) return;
    int dst = node0 + perm[node0 + threadIdx.x];  // sorted: wave gets similar degrees
    int rs = rowptr[dst], re = rowptr[dst + 1];
    float2 sdv = sd1[dst];
    float q0 = 0, qx0 = 0, qx1 = 0, qx2 = 0;
    float q1 = 0, qy0 = 0, qy1 = 0, qy2 = 0;
#define AGGA_EDGE(rr) { \
        float s0h, s1h; unpack_scores(rr.w, s0h, s1h); \
        float w0 = exp2f(lrelu(s0h + sdv.x)); \
        float w1 = exp2f(lrelu(s1h + sdv.y)); \
        q0 += w0; qx0 += w0 * rr.x; qx1 += w0 * rr.y; qx2 += w0 * rr.z; \
        q1 += w1; qy0 += w1 * rr.x; qy1 += w1 * rr.y; qy2 += w1 * rr.z; }
    int e = rs;
    for (; e + 4 <= re; e += 4) {
        int s0 = csr[e], s1 = csr[e + 1], s2 = csr[e + 2], s3 = csr[e + 3];
        float4 r0 = nrec4[s0], r1 = nrec4[s1], r2 = nrec4[s2], r3 = nrec4[s3];
        AGGA_EDGE(r0); AGGA_EDGE(r1); AGGA_EDGE(r2); AGGA_EDGE(r3);
    }
    for (; e < re; e++) {
        int s = csr[e];
        float4 r = nrec4[s];
        AGGA_EDGE(r);
    }
#undef AGGA_EDGE
    float inv0 = 1.f / (q0 + 1e-16f), inv1 = 1.f / (q1 + 1e-16f);
    float ax0 = qx0 * inv0, ax1 = qx1 * inv0, ax2 = qx2 * inv0;
    float ay0 = qy0 * inv1, ay1 = qy1 * inv1, ay2 = qy2 * inv1;
    float ps0 = 0, ps1 = 0, pd0 = 0, pd1 = 0;
    float4 out[4];
    __half2* ghp = (__half2*)out;
    float gprev = 0.f;
#pragma unroll
    for (int c = 0; c < 32; c++) {
        float v0 = W1[c * 3] * ax0 + W1[c * 3 + 1] * ax1 + W1[c * 3 + 2] * ax2;
        float v1 = W1[96 + c * 3] * ay0 + W1[97 + c * 3] * ay1 + W1[98 + c * 3] * ay2;
        float g = fmaxf(0.5f * (v0 + v1) + b1[c], 0.f);  // mean heads + bias + relu
        ps0 += g * u_s[c];      ps1 += g * u_s[32 + c];   // u_* already log2e-scaled
        pd0 += g * u_d[c];      pd1 += g * u_d[32 + c];
        if (c & 1) ghp[c >> 1] = __floats2half2_rn(gprev, g);
        else gprev = g;
    }
    float4* gdst = (float4*)(g1h + (size_t)dst * 16);
    gdst[0] = out[0]; gdst[1] = out[1]; gdst[2] = out[2]; gdst[3] = out[3];
    ssd2[dst] = make_float2(ps0, ps1);
    sd2[dst]  = make_float2(pd0, pd1);
}

// ---------------- FUSED: GAT2 aggregate (quad-per-dst, degree-sorted) + W2 + GRU (+fc) ----------------
// R9 geometry: 64 dsts/block, fp32 a_lds stride 65 (no bank conflicts), wave-uniform cg8.
__global__ __launch_bounds__(256) void aggBdense_kernel(
        const int* __restrict__ rowptr, const int* __restrict__ csr,
        const unsigned char* __restrict__ perm,
        const __half2* __restrict__ g1h,
        const float2* __restrict__ ssd2, const float2* __restrict__ sd2,
        const float* __restrict__ w2pk, const float* __restrict__ b2,
        const float* __restrict__ wgru,
        const float* __restrict__ b_ih, const float* __restrict__ b_hh,
        float* __restrict__ hstT, const float* __restrict__ fc_w,
        const float* __restrict__ fc_b, float* __restrict__ out,
        int N, int first, int last) {
    __shared__ float a_lds[64 * 65];     // [nl][k] stride 65 (reused for fc partials on last)
    __shared__ float g_lds[64 * 33];     // [nl][c]
    __shared__ float h_lds[64 * 33];     // [nl][k]
    int tid = threadIdx.x;
    int node0 = blockIdx.x * 64;
    // stage previous h state (coalesced: node fastest)
    for (int idx = tid; idx < 32 * 64; idx += 256) {
        int k = idx >> 6, nl = idx & 63;
        float hv = 0.f;
        if (!first && node0 + nl < N) hv = hstT[(size_t)k * N + node0 + nl];
        h_lds[nl * 33 + k] = hv;
    }
    // ---- phase 1: quad-per-dst GAT2 aggregation over degree-sorted slots ----
    int dl0 = tid >> 2;          // sorted-rank slot 0..63
    int q = tid & 3;             // quarter: channels q*8..q*8+7 per head
    if (node0 + dl0 < N) {
        int dl = perm[node0 + dl0];      // local dst index (bijective within tile)
        int dst = node0 + dl;
        int rs = rowptr[dst], re = rowptr[dst + 1];
        float2 sdv = sd2[dst];
        float a0[8] = {0, 0, 0, 0, 0, 0, 0, 0};
        float a1[8] = {0, 0, 0, 0, 0, 0, 0, 0};
        float den0 = 0.f, den1 = 0.f;
        const __half2* gbase = g1h + q * 4;
#define AGGB_EDGE(sc, gv) { \
        float w0 = exp2f(lrelu(sc.x + sdv.x)); \
        float w1 = exp2f(lrelu(sc.y + sdv.y)); \
        den0 += w0; den1 += w1; \
        float2 p0 = __half22float2(*(const __half2*)&gv.x); \
        float2 p1 = __half22float2(*(const __half2*)&gv.y); \
        float2 p2 = __half22float2(*(const __half2*)&gv.z); \
        float2 p3 = __half22float2(*(const __half2*)&gv.w); \
        a0[0] += w0 * p0.x; a0[1] += w0 * p0.y; a0[2] += w0 * p1.x; a0[3] += w0 * p1.y; \
        a0[4] += w0 * p2.x; a0[5] += w0 * p2.y; a0[6] += w0 * p3.x; a0[7] += w0 * p3.y; \
        a1[0] += w1 * p0.x; a1[1] += w1 * p0.y; a1[2] += w1 * p1.x; a1[3] += w1 * p1.y; \
        a1[4] += w1 * p2.x; a1[5] += w1 * p2.y; a1[6] += w1 * p3.x; a1[7] += w1 * p3.y; }
        int e = rs;
        for (; e + 4 <= re; e += 4) {
            int s0 = csr[e], s1 = csr[e + 1], s2 = csr[e + 2], s3 = csr[e + 3];
            float2 c0 = ssd2[s0], c1 = ssd2[s1], c2 = ssd2[s2], c3 = ssd2[s3];
            float4 g0 = *(const float4*)(gbase + (size_t)s0 * 16);
            float4 g1 = *(const float4*)(gbase + (size_t)s1 * 16);
            float4 g2 = *(const float4*)(gbase + (size_t)s2 * 16);
            float4 g3 = *(const float4*)(gbase + (size_t)s3 * 16);
            AGGB_EDGE(c0, g0); AGGB_EDGE(c1, g1); AGGB_EDGE(c2, g2); AGGB_EDGE(c3, g3);
        }
        for (; e < re; e++) {
            int s = csr[e];
            float2 c = ssd2[s];
            float4 g = *(const float4*)(gbase + (size_t)s * 16);
            AGGB_EDGE(c, g);
        }
#undef AGGB_EDGE
        float i0 = 1.f / (den0 + 1e-16f), i1 = 1.f / (den1 + 1e-16f);
#pragma unroll
        for (int j = 0; j < 8; j++) {
            a_lds[dl * 65 + q * 8 + j] = a0[j] * i0;
            a_lds[dl * 65 + 32 + q * 8 + j] = a1[j] * i1;
        }
    }
    __syncthreads();
    // ---- phase 2: W2 + mean-heads + relu (wave-uniform channel group -> s_load weights) ----
    int nl = tid & 63;
    int cg8 = __builtin_amdgcn_readfirstlane((tid >> 6) * 8);
    int node = node0 + nl;
    bool active = node < N;
    float acc[8] = {0, 0, 0, 0, 0, 0, 0, 0};
    for (int k = 0; k < 32; k++) {
        float ak0 = a_lds[nl * 65 + k];
        float ak1 = a_lds[nl * 65 + 32 + k];
        const float* wp = w2pk + k * 64 + cg8;
#pragma unroll
        for (int j = 0; j < 8; j++) acc[j] += wp[j] * ak0 + wp[32 + j] * ak1;
    }
#pragma unroll
    for (int j = 0; j < 8; j++) {
        float g = fmaxf(0.5f * acc[j] + b2[cg8 + j], 0.f);
        g_lds[nl * 33 + cg8 + j] = g;
    }
    __syncthreads();
    // ---- GRU for channels cg8..cg8+7 ----
    float ir[8], iz[8], in_[8], hr[8], hz[8], hn[8];
#pragma unroll
    for (int j = 0; j < 8; j++) {
        ir[j] = b_ih[cg8 + j]; iz[j] = b_ih[32 + cg8 + j]; in_[j] = b_ih[64 + cg8 + j];
        hr[j] = b_hh[cg8 + j]; hz[j] = b_hh[32 + cg8 + j]; hn[j] = b_hh[64 + cg8 + j];
    }
    for (int k = 0; k < 32; k++) {
        float gk = g_lds[nl * 33 + k];
        float hk = h_lds[nl * 33 + k];
        const float* wp = wgru + k * 192 + cg8;
#pragma unroll
        for (int j = 0; j < 8; j++) {
            ir[j]  += wp[j]       * gk;
            iz[j]  += wp[32 + j]  * gk;
            in_[j] += wp[64 + j]  * gk;
            hr[j]  += wp[96 + j]  * hk;
            hz[j]  += wp[128 + j] * hk;
            hn[j]  += wp[160 + j] * hk;
        }
    }
    float part = 0.f;
    if (active) {
#pragma unroll
        for (int j = 0; j < 8; j++) {
            int c = cg8 + j;
            float rr = sigmoidf(ir[j] + hr[j]);
            float zz = sigmoidf(iz[j] + hz[j]);
            float cand = tanhf(in_[j] + rr * hn[j]);
            float hold = h_lds[nl * 33 + c];
            float hnew = (1.f - zz) * cand + zz * hold;
            if (!last) hstT[(size_t)c * N + node] = hnew;
            else part += fc_w[c] * hnew;
        }
    }
    if (last) {
        __syncthreads();  // a_lds no longer needed; reuse for fc partials
        a_lds[nl * 5 + (tid >> 6)] = part;
        __syncthreads();
        if (tid < 64 && node0 + tid < N) {
            float v = a_lds[tid * 5] + a_lds[tid * 5 + 1] + a_lds[tid * 5 + 2] +
                      a_lds[tid * 5 + 3] + fc_b[0];
            out[node0 + tid] = v;
        }
    }
}

extern "C" void kernel_launch(void* const* d_in, const int* in_sizes, int n_in,
                              void* d_out, int out_size, void* d_ws, size_t ws_size,
                              hipStream_t stream) {
    const float* x_seq = (const float*)d_in[0];
    const float* W1  = (const float*)d_in[1];
    const float* a1s = (const float*)d_in[2];
    const float* a1d = (const float*)d_in[3];
    const float* b1  = (const float*)d_in[4];
    const float* W2  = (const float*)d_in[5];
    const float* a2s = (const float*)d_in[6];
    const float* a2d = (const float*)d_in[7];
    const float* b2  = (const float*)d_in[8];
    const float* w_ih = (const float*)d_in[9];
    const float* w_hh = (const float*)d_in[10];
    const float* b_ih = (const float*)d_in[11];
    const float* b_hh = (const float*)d_in[12];
    const float* fc_w = (const float*)d_in[13];
    const float* fc_b = (const float*)d_in[14];
    const void*  ei   = d_in[15];

    const int N = in_sizes[0] / (T_STEPS * FIN);  // 50000
    const int E = in_sizes[15] / 2;               // 800000
    const int NE = E + N;
    const int NB = (N + 255) / 256;               // per-256 blocks (196)
    const int NB64 = (N + 63) / 64;               // 64-node blocks (782)
    const int EB = (E + 255) / 256;

    char* ws = (char*)d_ws;
    size_t off = 0;
    auto alloc = [&](size_t bytes) -> void* {
        void* p = ws + off;
        off += (bytes + 255) & ~(size_t)255;
        return p;
    };
    int*           flag   = (int*)alloc(4);
    int*           rowptr = (int*)alloc((size_t)(N + 1) * 4);
    int*           cnt    = (int*)alloc((size_t)N * 4);     // reused as fill cursor
    int*           bsum   = (int*)alloc(256 * 4);
    int*           csr    = (int*)alloc((size_t)NE * 4);
    int*           src32  = (int*)alloc((size_t)E * 4);
    int*           dst32  = (int*)alloc((size_t)E * 4);
    float4*        nrec4  = (float4*)alloc((size_t)N * 16); // {x0,x1,x2,half2(ss0,ss1)*log2e}
    float2*        sd1    = (float2*)alloc((size_t)N * 8);
    float2*        ssd2   = (float2*)alloc((size_t)N * 8);
    float2*        sd2    = (float2*)alloc((size_t)N * 8);
    __half2*       g1h    = (__half2*)alloc((size_t)N * 16 * 4);  // fp16 g1: 64B/node
    float*         hstT   = (float*)alloc((size_t)N * 32 * 4);    // transposed hstate [c][node]
    unsigned char* perm   = (unsigned char*)alloc((size_t)N);     // per-64-tile degree rank
    float*         u_s    = (float*)alloc(64 * 4);
    float*         u_d    = (float*)alloc(64 * 4);
    float*         w2pk   = (float*)alloc(2048 * 4);              // k-major W2
    float*         wgru   = (float*)alloc(6144 * 4);              // k-major GRU weights
    if (off > ws_size) return;  // workspace too small — cannot proceed safely

    // ---- preprocessing: CSR by destination (reused for all 16 aggregations) ----
    detect_kernel<<<1, 128, 0, stream>>>((const int*)ei, in_sizes[15], flag);
    init_kernel<<<NB, 256, 0, stream>>>(cnt, N);
    conv_count_kernel<<<EB, 256, 0, stream>>>(ei, flag, E, N, src32, dst32, cnt);
    scan1_kernel<<<NB, 256, 0, stream>>>(cnt, rowptr, bsum, N);
    scan2_kernel<<<1, 256, 0, stream>>>(bsum, NB);
    scan3_kernel<<<NB, 256, 0, stream>>>(rowptr, bsum, N);
    selffill_kernel<<<NB, 256, 0, stream>>>(rowptr, csr, cnt, N);
    {
        const int NPASS = 4;
        int per = (N + NPASS - 1) / NPASS;
        for (int p = 0; p < NPASS; p++) {
            int lo = p * per;
            int hi = min(lo + per, N);
            scatter_kernel<<<EB, 256, 0, stream>>>(src32, dst32, E, lo, hi, cnt, csr);
        }
    }
    sortperm_kernel<<<NB64, 64, 0, stream>>>(rowptr, perm, N);
    prep_u_kernel<<<1, 64, 0, stream>>>(W2, a2s, a2d, u_s, u_d);
    pack_kernel<<<24, 256, 0, stream>>>(W2, w_ih, w_hh, w2pk, wgru);

    // ---- T timesteps ----
    for (int t = 0; t < T_STEPS; t++) {
        const float* xt = x_seq + (size_t)t * N * FIN;
        score1_kernel<<<NB, 256, 0, stream>>>(xt, W1, a1s, a1d, nrec4, sd1, N);
        aggA_kernel<<<NB64, 64, 0, stream>>>(rowptr, csr, perm, nrec4, sd1, W1, b1,
                                             u_s, u_d, g1h, ssd2, sd2, N);
        aggBdense_kernel<<<NB64, 256, 0, stream>>>(rowptr, csr, perm, g1h, ssd2, sd2,
                                                   w2pk, b2, wgru, b_ih, b_hh,
                                                   hstT, fc_w, fc_b, (float*)d_out,
                                                   N, t == 0 ? 1 : 0, t == T_STEPS - 1 ? 1 : 0);
    }
}

// Round 13
// 423.465 us; speedup vs baseline: 1.8936x; 1.3375x over previous
//
#include <hip/hip_runtime.h>
#include <hip/hip_fp16.h>
#include <stdint.h>

#define T_STEPS 8
#define FIN 3
#define HID 32
#define NEG_SLOPE 0.2f
#define LOG2E 1.4426950408889634f

__device__ __forceinline__ float lrelu(float x) { return x > 0.f ? x : NEG_SLOPE * x; }
__device__ __forceinline__ float sigmoidf(float x) { return 1.f / (1.f + __expf(-x)); }

// ---------------- edge dtype detection (int64 vs int32) ----------------
__global__ void detect_kernel(const int* ei32, int nElems, int* flag) {
    __shared__ int any_nonzero;
    if (threadIdx.x == 0) any_nonzero = 0;
    __syncthreads();
    int idx = 1 + 2 * (int)threadIdx.x;  // odd int32 slots
    if (idx < nElems && ei32[idx] != 0) any_nonzero = 1;  // benign race
    __syncthreads();
    if (threadIdx.x == 0) *flag = (any_nonzero ? 0 : 1);  // 1 => int64
}

__device__ __forceinline__ int get_edge(const void* ei, int is64, long long idx) {
    if (is64) return (int)((const long long*)ei)[idx];
    return ((const int*)ei)[idx];
}

__global__ void init_kernel(int* cnt, int N) {
    int i = blockIdx.x * 256 + threadIdx.x;
    if (i < N) cnt[i] = 1;  // self-loop pre-counted
}

// fused: int32 conversion + validity clamp + per-dst count
__global__ void conv_count_kernel(const void* ei, const int* flag, int E, int N,
                                  int* src32, int* dst32, int* cnt) {
    int e = blockIdx.x * 256 + threadIdx.x;
    if (e >= E) return;
    int is64 = *flag;
    int s = get_edge(ei, is64, e);
    int d = get_edge(ei, is64, (long long)E + e);
    if ((unsigned)s >= (unsigned)N) s = 0;  // safety clamp
    src32[e] = s;
    int dd = ((unsigned)d < (unsigned)N) ? d : 0x7fffffff;  // sentinel: excluded everywhere
    dst32[e] = dd;
    if (dd < N) atomicAdd(&cnt[dd], 1);
}

// hierarchical scan
__global__ __launch_bounds__(256) void scan1_kernel(const int* cnt, int* rowptr, int* bsum, int n) {
    __shared__ int sm[256];
    int i = blockIdx.x * 256 + threadIdx.x;
    int v = (i < n) ? cnt[i] : 0;
    sm[threadIdx.x] = v;
    __syncthreads();
    for (int off = 1; off < 256; off <<= 1) {
        int t = (threadIdx.x >= off) ? sm[threadIdx.x - off] : 0;
        __syncthreads();
        sm[threadIdx.x] += t;
        __syncthreads();
    }
    if (i < n) rowptr[i + 1] = sm[threadIdx.x];
    if (threadIdx.x == 255) bsum[blockIdx.x] = sm[255];
}

__global__ __launch_bounds__(256) void scan2_kernel(int* bsum, int nb) {
    __shared__ int sm[256];
    int v = (threadIdx.x < nb) ? bsum[threadIdx.x] : 0;
    sm[threadIdx.x] = v;
    __syncthreads();
    for (int off = 1; off < 256; off <<= 1) {
        int t = (threadIdx.x >= off) ? sm[threadIdx.x - off] : 0;
        __syncthreads();
        sm[threadIdx.x] += t;
        __syncthreads();
    }
    if (threadIdx.x < nb) bsum[threadIdx.x] = sm[threadIdx.x];
}

__global__ __launch_bounds__(256) void scan3_kernel(int* rowptr, const int* bsum, int n) {
    int i = blockIdx.x * 256 + threadIdx.x;
    if (i < n && blockIdx.x > 0) rowptr[i + 1] += bsum[blockIdx.x - 1];
    if (i == 0) rowptr[0] = 0;
}

__global__ void selffill_kernel(const int* rowptr, int* csr, int* fill, int N) {
    int n = blockIdx.x * 256 + threadIdx.x;
    if (n >= N) return;
    int rp = rowptr[n];
    csr[rp] = n;        // self-loop occupies slot 0 of each row
    fill[n] = rp + 1;
}

// dst-sliced scatter: csr writes confined to an L2-resident window per pass
__global__ void scatter_kernel(const int* __restrict__ src32, const int* __restrict__ dst32,
                               int E, int lo, int hi, int* fill, int* csr) {
    int e = blockIdx.x * 256 + threadIdx.x;
    if (e >= E) return;
    int d = dst32[e];
    if (d < lo || d >= hi) return;
    int p = atomicAdd(&fill[d], 1);
    csr[p] = src32[e];
}

// ---------------- precompute u = (W2^T a2) * log2(e) per head ----------------
__global__ __launch_bounds__(64) void prep_u_kernel(
        const float* __restrict__ W2, const float* __restrict__ a2s,
        const float* __restrict__ a2d, float* __restrict__ u_s, float* __restrict__ u_d) {
    int l = threadIdx.x;  // 0..63
    int h = l >> 5, k = l & 31;
    float us = 0.f, ud = 0.f;
    for (int c = 0; c < 32; c++) {
        float w = W2[(h * 32 + c) * 32 + k];
        us += a2s[h * 32 + c] * w;
        ud += a2d[h * 32 + c] * w;
    }
    u_s[l] = us * LOG2E;   // exp2 trick: lrelu is positively homogeneous
    u_d[l] = ud * LOG2E;
}

// ---------------- pack weights k-major for the dense phase ----------------
__global__ __launch_bounds__(256) void pack_kernel(
        const float* __restrict__ W2, const float* __restrict__ w_ih,
        const float* __restrict__ w_hh, float* __restrict__ w2pk, float* __restrict__ wgru) {
    int idx = blockIdx.x * 256 + threadIdx.x;
    if (idx < 2048) {
        int k = idx >> 6, c = idx & 63;
        w2pk[idx] = W2[c * 32 + k];
    }
    if (idx < 6144) {
        int k = idx / 192, r = idx % 192;
        wgru[idx] = (r < 96) ? w_ih[r * 32 + k] : w_hh[(r - 96) * 32 + k];
    }
}

// ---------------- ALL timesteps layer-1 scores (t = blockIdx.x -> per-XCD) ----------------
__global__ __launch_bounds__(256) void score1_all(
        const float* __restrict__ x_seq, const float* __restrict__ W1,
        const float* __restrict__ a1s, const float* __restrict__ a1d,
        float4* __restrict__ nrec4, float2* __restrict__ sd1, int N) {
    int t = blockIdx.x;
    int node = blockIdx.y * 256 + threadIdx.x;
    if (node >= N) return;
    const float* xp = x_seq + ((size_t)t * N + node) * FIN;
    float x0 = xp[0], x1 = xp[1], x2 = xp[2];
    float ps0 = 0.f, ps1 = 0.f, pd0 = 0.f, pd1 = 0.f;
    for (int c = 0; c < 32; c++) {
        float h0 = W1[c * 3] * x0 + W1[c * 3 + 1] * x1 + W1[c * 3 + 2] * x2;
        float h1 = W1[96 + c * 3] * x0 + W1[97 + c * 3] * x1 + W1[98 + c * 3] * x2;
        ps0 += h0 * a1s[c]; pd0 += h0 * a1d[c];
        ps1 += h1 * a1s[32 + c]; pd1 += h1 * a1d[32 + c];
    }
    ps0 *= LOG2E; ps1 *= LOG2E; pd0 *= LOG2E; pd1 *= LOG2E;
    unsigned u = (unsigned)__half_as_ushort(__float2half_rn(ps0)) |
                 ((unsigned)__half_as_ushort(__float2half_rn(ps1)) << 16);
    float4 r;
    r.x = x0; r.y = x1; r.z = x2; r.w = __uint_as_float(u);
    nrec4[(size_t)t * N + node] = r;
    sd1[(size_t)t * N + node] = make_float2(pd0, pd1);
}

__device__ __forceinline__ void unpack_scores(float wslot, float& s0, float& s1) {
    unsigned u = __float_as_uint(wslot);
    s0 = __half2float(__ushort_as_half((unsigned short)(u & 0xffffu)));
    s1 = __half2float(__ushort_as_half((unsigned short)(u >> 16)));
}

// ---------------- ALL timesteps GAT1 aggregate: thread-per-(dst,t) ----------------
// grid (8, NB64): t = blockIdx.x -> each XCD's L2 holds its own t's nrec4 table.
__global__ __launch_bounds__(64) void aggA_all(
        const int* __restrict__ rowptr, const int* __restrict__ csr,
        const float4* __restrict__ nrec4, const float2* __restrict__ sd1,
        const float* __restrict__ W1, const float* __restrict__ b1,
        const float* __restrict__ u_s, const float* __restrict__ u_d,
        __half2* __restrict__ g1h, float2* __restrict__ ssd2, float2* __restrict__ sd2, int N) {
    int t = blockIdx.x;
    int dst = blockIdx.y * 64 + threadIdx.x;
    if (dst >= N) return;
    const float4* nr = nrec4 + (size_t)t * N;
    int rs = rowptr[dst], re = rowptr[dst + 1];
    float2 sdv = sd1[(size_t)t * N + dst];
    float q0 = 0, qx0 = 0, qx1 = 0, qx2 = 0;
    float q1 = 0, qy0 = 0, qy1 = 0, qy2 = 0;
#define AGGA_EDGE(rr) { \
        float s0h, s1h; unpack_scores(rr.w, s0h, s1h); \
        float w0 = exp2f(lrelu(s0h + sdv.x)); \
        float w1 = exp2f(lrelu(s1h + sdv.y)); \
        q0 += w0; qx0 += w0 * rr.x; qx1 += w0 * rr.y; qx2 += w0 * rr.z; \
        q1 += w1; qy0 += w1 * rr.x; qy1 += w1 * rr.y; qy2 += w1 * rr.z; }
    int e = rs;
    for (; e + 4 <= re; e += 4) {
        int s0 = csr[e], s1 = csr[e + 1], s2 = csr[e + 2], s3 = csr[e + 3];
        float4 r0 = nr[s0], r1 = nr[s1], r2 = nr[s2], r3 = nr[s3];
        AGGA_EDGE(r0); AGGA_EDGE(r1); AGGA_EDGE(r2); AGGA_EDGE(r3);
    }
    for (; e < re; e++) {
        float4 r = nr[csr[e]];
        AGGA_EDGE(r);
    }
#undef AGGA_EDGE
    float inv0 = 1.f / (q0 + 1e-16f), inv1 = 1.f / (q1 + 1e-16f);
    float ax0 = qx0 * inv0, ax1 = qx1 * inv0, ax2 = qx2 * inv0;
    float ay0 = qy0 * inv1, ay1 = qy1 * inv1, ay2 = qy2 * inv1;
    float ps0 = 0, ps1 = 0, pd0 = 0, pd1 = 0;
    float4 out[4];
    __half2* ghp = (__half2*)out;
    float gprev = 0.f;
#pragma unroll
    for (int c = 0; c < 32; c++) {
        float v0 = W1[c * 3] * ax0 + W1[c * 3 + 1] * ax1 + W1[c * 3 + 2] * ax2;
        float v1 = W1[96 + c * 3] * ay0 + W1[97 + c * 3] * ay1 + W1[98 + c * 3] * ay2;
        float g = fmaxf(0.5f * (v0 + v1) + b1[c], 0.f);  // mean heads + bias + relu
        ps0 += g * u_s[c];      ps1 += g * u_s[32 + c];   // u_* already log2e-scaled
        pd0 += g * u_d[c];      pd1 += g * u_d[32 + c];
        if (c & 1) ghp[c >> 1] = __floats2half2_rn(gprev, g);
        else gprev = g;
    }
    float4* gdst = (float4*)(g1h + (size_t)t * N * 16 + (size_t)dst * 16);
    gdst[0] = out[0]; gdst[1] = out[1]; gdst[2] = out[2]; gdst[3] = out[3];
    ssd2[(size_t)t * N + dst] = make_float2(ps0, ps1);
    sd2[(size_t)t * N + dst]  = make_float2(pd0, pd1);
}

// ---------------- ALL timesteps GAT2 aggregate: quad-per-(dst,t) -> fp16 agg ----------------
// grid (8, NB64): XCD i caches only timestep i's 3.2MB g1h table (fits 4MB L2).
__global__ __launch_bounds__(256) void aggBg_all(
        const int* __restrict__ rowptr, const int* __restrict__ csr,
        const __half2* __restrict__ g1h,
        const float2* __restrict__ ssd2, const float2* __restrict__ sd2,
        __half2* __restrict__ aggH, int N) {
    int t = blockIdx.x;
    int dl = threadIdx.x >> 2;   // local dst 0..63
    int q = threadIdx.x & 3;     // quarter: channels q*8..q*8+7 per head
    int dst = blockIdx.y * 64 + dl;
    if (dst >= N) return;
    const __half2* gbase = g1h + (size_t)t * N * 16 + q * 4;
    const float2* ss = ssd2 + (size_t)t * N;
    int rs = rowptr[dst], re = rowptr[dst + 1];
    float2 sdv = sd2[(size_t)t * N + dst];
    float a0[8] = {0, 0, 0, 0, 0, 0, 0, 0};
    float a1[8] = {0, 0, 0, 0, 0, 0, 0, 0};
    float den0 = 0.f, den1 = 0.f;
#define AGGB_EDGE(sc, gv) { \
        float w0 = exp2f(lrelu(sc.x + sdv.x)); \
        float w1 = exp2f(lrelu(sc.y + sdv.y)); \
        den0 += w0; den1 += w1; \
        float2 p0 = __half22float2(*(const __half2*)&gv.x); \
        float2 p1 = __half22float2(*(const __half2*)&gv.y); \
        float2 p2 = __half22float2(*(const __half2*)&gv.z); \
        float2 p3 = __half22float2(*(const __half2*)&gv.w); \
        a0[0] += w0 * p0.x; a0[1] += w0 * p0.y; a0[2] += w0 * p1.x; a0[3] += w0 * p1.y; \
        a0[4] += w0 * p2.x; a0[5] += w0 * p2.y; a0[6] += w0 * p3.x; a0[7] += w0 * p3.y; \
        a1[0] += w1 * p0.x; a1[1] += w1 * p0.y; a1[2] += w1 * p1.x; a1[3] += w1 * p1.y; \
        a1[4] += w1 * p2.x; a1[5] += w1 * p2.y; a1[6] += w1 * p3.x; a1[7] += w1 * p3.y; }
    int e = rs;
    for (; e + 4 <= re; e += 4) {
        int s0 = csr[e], s1 = csr[e + 1], s2 = csr[e + 2], s3 = csr[e + 3];
        float2 c0 = ss[s0], c1 = ss[s1], c2 = ss[s2], c3 = ss[s3];
        float4 g0 = *(const float4*)(gbase + (size_t)s0 * 16);
        float4 g1 = *(const float4*)(gbase + (size_t)s1 * 16);
        float4 g2 = *(const float4*)(gbase + (size_t)s2 * 16);
        float4 g3 = *(const float4*)(gbase + (size_t)s3 * 16);
        AGGB_EDGE(c0, g0); AGGB_EDGE(c1, g1); AGGB_EDGE(c2, g2); AGGB_EDGE(c3, g3);
    }
    for (; e < re; e++) {
        int s = csr[e];
        float2 c = ss[s];
        float4 g = *(const float4*)(gbase + (size_t)s * 16);
        AGGB_EDGE(c, g);
    }
#undef AGGB_EDGE
    float i0 = 1.f / (den0 + 1e-16f), i1 = 1.f / (den1 + 1e-16f);
    __half2 o0[4], o1[4];
#pragma unroll
    for (int j = 0; j < 4; j++) {
        o0[j] = __floats2half2_rn(a0[2 * j] * i0, a0[2 * j + 1] * i0);
        o1[j] = __floats2half2_rn(a1[2 * j] * i1, a1[2 * j + 1] * i1);
    }
    __half2* row = aggH + (size_t)t * N * 32 + (size_t)dst * 32;  // 32 half2 = 128B/row
    *(float4*)(row + q * 4)      = *(float4*)o0;   // head0 pairs q*4..q*4+3
    *(float4*)(row + 16 + q * 4) = *(float4*)o1;   // head1 pairs
    // quad covers bytes [0,64)+[64,128): fully coalesced
}

// ---------------- ONE kernel: all 8 GRU steps, h resident in LDS, fused final fc ----------------
__global__ __launch_bounds__(256) void gru_all(
        const __half2* __restrict__ aggH,
        const float* __restrict__ w2pk, const float* __restrict__ b2,
        const float* __restrict__ wgru,
        const float* __restrict__ b_ih, const float* __restrict__ b_hh,
        const float* __restrict__ fc_w, const float* __restrict__ fc_b,
        float* __restrict__ out, int N) {
    __shared__ __half2 a_lds[64 * 33];   // [nl][pair 0..31] (0-15 head0, 16-31 head1)
    __shared__ float g_lds[64 * 33];     // [nl][c] (reused for fc partials at the end)
    __shared__ float h_lds[64 * 33];     // [nl][k]
    int tid = threadIdx.x;
    int node0 = blockIdx.x * 64;
    int nl = tid & 63;
    int cg8 = __builtin_amdgcn_readfirstlane((tid >> 6) * 8);  // wave-uniform channel base
    int node = node0 + nl;
    bool active = node < N;
    for (int idx = tid; idx < 64 * 33; idx += 256) h_lds[idx] = 0.f;
    float part = 0.f;
    for (int t = 0; t < T_STEPS; t++) {
        __syncthreads();
        // stage this tile's agg rows for timestep t (64 rows x 128B, coalesced float4)
        const float4* src = (const float4*)(aggH + (size_t)t * N * 32 + (size_t)node0 * 32);
        for (int idx = tid; idx < 512; idx += 256) {
            int rr = idx >> 3, p4 = idx & 7;
            if (node0 + rr < N) {
                float4 v = src[rr * 8 + p4];
                *(float4*)&a_lds[rr * 33 + p4 * 4] = v;
            }
        }
        __syncthreads();
        // ---- W2 + mean-heads + relu ----
        float acc[8] = {0, 0, 0, 0, 0, 0, 0, 0};
        for (int kp = 0; kp < 16; kp++) {
            float2 A0 = __half22float2(a_lds[nl * 33 + kp]);
            float2 A1 = __half22float2(a_lds[nl * 33 + 16 + kp]);
            const float* wpA = w2pk + (2 * kp) * 64 + cg8;
            const float* wpB = w2pk + (2 * kp + 1) * 64 + cg8;
#pragma unroll
            for (int j = 0; j < 8; j++)
                acc[j] += wpA[j] * A0.x + wpA[32 + j] * A1.x + wpB[j] * A0.y + wpB[32 + j] * A1.y;
        }
#pragma unroll
        for (int j = 0; j < 8; j++) {
            float g = fmaxf(0.5f * acc[j] + b2[cg8 + j], 0.f);
            g_lds[nl * 33 + cg8 + j] = g;
        }
        __syncthreads();
        // ---- GRU for channels cg8..cg8+7 ----
        float ir[8], iz[8], in_[8], hr[8], hz[8], hn[8];
#pragma unroll
        for (int j = 0; j < 8; j++) {
            ir[j] = b_ih[cg8 + j]; iz[j] = b_ih[32 + cg8 + j]; in_[j] = b_ih[64 + cg8 + j];
            hr[j] = b_hh[cg8 + j]; hz[j] = b_hh[32 + cg8 + j]; hn[j] = b_hh[64 + cg8 + j];
        }
        for (int k = 0; k < 32; k++) {
            float gk = g_lds[nl * 33 + k];
            float hk = h_lds[nl * 33 + k];
            const float* wp = wgru + k * 192 + cg8;
#pragma unroll
            for (int j = 0; j < 8; j++) {
                ir[j]  += wp[j]       * gk;
                iz[j]  += wp[32 + j]  * gk;
                in_[j] += wp[64 + j]  * gk;
                hr[j]  += wp[96 + j]  * hk;
                hz[j]  += wp[128 + j] * hk;
                hn[j]  += wp[160 + j] * hk;
            }
        }
        float hnew[8];
#pragma unroll
        for (int j = 0; j < 8; j++) {
            float rr = sigmoidf(ir[j] + hr[j]);
            float zz = sigmoidf(iz[j] + hz[j]);
            float cand = tanhf(in_[j] + rr * hn[j]);
            float hold = h_lds[nl * 33 + cg8 + j];
            hnew[j] = (1.f - zz) * cand + zz * hold;
        }
        __syncthreads();  // all reads of old h done before overwrite
#pragma unroll
        for (int j = 0; j < 8; j++) h_lds[nl * 33 + cg8 + j] = hnew[j];
        if (t == T_STEPS - 1 && active) {
#pragma unroll
            for (int j = 0; j < 8; j++) part += fc_w[cg8 + j] * hnew[j];
        }
    }
    __syncthreads();  // g_lds free; reuse for fc partials
    g_lds[nl * 5 + (tid >> 6)] = part;
    __syncthreads();
    if (tid < 64 && node0 + tid < N) {
        float v = g_lds[tid * 5] + g_lds[tid * 5 + 1] + g_lds[tid * 5 + 2] +
                  g_lds[tid * 5 + 3] + fc_b[0];
        out[node0 + tid] = v;
    }
}

extern "C" void kernel_launch(void* const* d_in, const int* in_sizes, int n_in,
                              void* d_out, int out_size, void* d_ws, size_t ws_size,
                              hipStream_t stream) {
    const float* x_seq = (const float*)d_in[0];
    const float* W1  = (const float*)d_in[1];
    const float* a1s = (const float*)d_in[2];
    const float* a1d = (const float*)d_in[3];
    const float* b1  = (const float*)d_in[4];
    const float* W2  = (const float*)d_in[5];
    const float* a2s = (const float*)d_in[6];
    const float* a2d = (const float*)d_in[7];
    const float* b2  = (const float*)d_in[8];
    const float* w_ih = (const float*)d_in[9];
    const float* w_hh = (const float*)d_in[10];
    const float* b_ih = (const float*)d_in[11];
    const float* b_hh = (const float*)d_in[12];
    const float* fc_w = (const float*)d_in[13];
    const float* fc_b = (const float*)d_in[14];
    const void*  ei   = d_in[15];

    const int N = in_sizes[0] / (T_STEPS * FIN);  // 50000
    const int E = in_sizes[15] / 2;               // 800000
    const int NE = E + N;
    const int NB = (N + 255) / 256;               // per-256 blocks (196)
    const int NB64 = (N + 63) / 64;               // 64-node blocks (782)
    const int EB = (E + 255) / 256;

    char* ws = (char*)d_ws;
    size_t off = 0;
    auto alloc = [&](size_t bytes) -> void* {
        void* p = ws + off;
        off += (bytes + 255) & ~(size_t)255;
        return p;
    };
    int*     flag   = (int*)alloc(4);
    int*     rowptr = (int*)alloc((size_t)(N + 1) * 4);
    int*     cnt    = (int*)alloc((size_t)N * 4);        // reused as fill cursor
    int*     bsum   = (int*)alloc(256 * 4);
    int*     csr    = (int*)alloc((size_t)NE * 4);
    int*     src32  = (int*)alloc((size_t)E * 4);
    int*     dst32  = (int*)alloc((size_t)E * 4);
    float4*  nrec4  = (float4*)alloc((size_t)T_STEPS * N * 16);       // 6.4MB
    float2*  sd1    = (float2*)alloc((size_t)T_STEPS * N * 8);        // 3.2MB
    float2*  ssd2   = (float2*)alloc((size_t)T_STEPS * N * 8);        // 3.2MB
    float2*  sd2    = (float2*)alloc((size_t)T_STEPS * N * 8);        // 3.2MB
    __half2* g1h    = (__half2*)alloc((size_t)T_STEPS * N * 16 * 4);  // 25.6MB
    __half2* aggH   = (__half2*)alloc((size_t)T_STEPS * N * 32 * 4);  // 51.2MB
    float*   u_s    = (float*)alloc(64 * 4);
    float*   u_d    = (float*)alloc(64 * 4);
    float*   w2pk   = (float*)alloc(2048 * 4);              // k-major W2
    float*   wgru   = (float*)alloc(6144 * 4);              // k-major GRU weights
    if (off > ws_size) return;  // workspace too small — cannot proceed safely

    // ---- preprocessing: CSR by destination (reused for all 16 aggregations) ----
    detect_kernel<<<1, 128, 0, stream>>>((const int*)ei, in_sizes[15], flag);
    init_kernel<<<NB, 256, 0, stream>>>(cnt, N);
    conv_count_kernel<<<EB, 256, 0, stream>>>(ei, flag, E, N, src32, dst32, cnt);
    scan1_kernel<<<NB, 256, 0, stream>>>(cnt, rowptr, bsum, N);
    scan2_kernel<<<1, 256, 0, stream>>>(bsum, NB);
    scan3_kernel<<<NB, 256, 0, stream>>>(rowptr, bsum, N);
    selffill_kernel<<<NB, 256, 0, stream>>>(rowptr, csr, cnt, N);
    {
        const int NPASS = 4;
        int per = (N + NPASS - 1) / NPASS;
        for (int p = 0; p < NPASS; p++) {
            int lo = p * per;
            int hi = min(lo + per, N);
            scatter_kernel<<<EB, 256, 0, stream>>>(src32, dst32, E, lo, hi, cnt, csr);
        }
    }
    prep_u_kernel<<<1, 64, 0, stream>>>(W2, a2s, a2d, u_s, u_d);
    pack_kernel<<<24, 256, 0, stream>>>(W2, w_ih, w_hh, w2pk, wgru);

    // ---- ALL timesteps batched (only the GRU is serial) ----
    score1_all<<<dim3(T_STEPS, NB), 256, 0, stream>>>(x_seq, W1, a1s, a1d, nrec4, sd1, N);
    aggA_all<<<dim3(T_STEPS, NB64), 64, 0, stream>>>(rowptr, csr, nrec4, sd1, W1, b1,
                                                     u_s, u_d, g1h, ssd2, sd2, N);
    aggBg_all<<<dim3(T_STEPS, NB64), 256, 0, stream>>>(rowptr, csr, g1h, ssd2, sd2, aggH, N);
    gru_all<<<NB64, 256, 0, stream>>>(aggH, w2pk, b2, wgru, b_ih, b_hh,
                                      fc_w, fc_b, (float*)d_out, N);
}